// Round 4
// baseline (355.002 us; speedup 1.0000x reference)
//
#include <hip/hip_runtime.h>

#define DIMC 256
#define BSZ  32
#define MDIM 2048
#define NDIM 2048

typedef __attribute__((ext_vector_type(8))) short bf16x8;   // 8 bf16
typedef __attribute__((ext_vector_type(4))) float f32x4;    // MFMA acc

static __device__ __forceinline__ unsigned short f2bf(float x) {
  unsigned int u = __float_as_uint(x);
  u += 0x7fffu + ((u >> 16) & 1u);          // RNE
  return (unsigned short)(u >> 16);
}
static __device__ __forceinline__ float bf2f(unsigned short h) {
  return __uint_as_float(((unsigned int)h) << 16);
}

// async global->LDS, 16 B per lane; LDS dest is wave-uniform base + lane*16
static __device__ __forceinline__ void gl_lds16(const void* g, void* l) {
  __builtin_amdgcn_global_load_lds(
      (const __attribute__((address_space(1))) unsigned int*)g,
      (__attribute__((address_space(3))) unsigned int*)l, 16, 0, 0);
}

// ---------------------------------------------------------------------------
// Wt[e][c] = bf16(W[c][e])
// ---------------------------------------------------------------------------
__global__ __launch_bounds__(256) void wt_kernel(
    const float* __restrict__ W, unsigned short* __restrict__ Wt) {
  const int e = blockIdx.x, c = threadIdx.x;
  Wt[e * 256 + c] = f2bf(W[c * 256 + e]);
}

// ---------------------------------------------------------------------------
// Transpose+convert: tq[b][m][c] = bf16(query[b][c][m] / 16)
//                    tk[b][n][c] = bf16(key[b][c][n])
// 64x64 tiles through LDS; z<32 -> query, else key.
// ---------------------------------------------------------------------------
__global__ __launch_bounds__(256) void trans_kernel(
    const float* __restrict__ query, const float* __restrict__ key,
    unsigned short* __restrict__ tq, unsigned short* __restrict__ tk) {
  const int z = blockIdx.z;
  const int b = z & 31;
  const bool isq = z < 32;
  const float* in = (isq ? query : key) + (size_t)b * DIMC * MDIM;
  unsigned short* out = (isq ? tq : tk) + (size_t)b * MDIM * DIMC;
  const float alpha = isq ? 0.0625f : 1.0f;
  const int m0 = blockIdx.x * 64, c0 = blockIdx.y * 64;
  __shared__ float s[64][65];
  const int t = threadIdx.x;
  const int r16 = t >> 4, o4 = (t & 15) << 2;
#pragma unroll
  for (int p = 0; p < 4; ++p) {
    const int cl = p * 16 + r16;
    float4 v = *(const float4*)(in + (size_t)(c0 + cl) * MDIM + m0 + o4);
    s[cl][o4 + 0] = v.x; s[cl][o4 + 1] = v.y;
    s[cl][o4 + 2] = v.z; s[cl][o4 + 3] = v.w;
  }
  __syncthreads();
#pragma unroll
  for (int p = 0; p < 4; ++p) {
    const int ml = p * 16 + r16;
    unsigned short o[4] __attribute__((aligned(8)));
#pragma unroll
    for (int i = 0; i < 4; ++i) o[i] = f2bf(s[o4 + i][ml] * alpha);
    *(uint2*)(out + (size_t)(m0 + ml) * DIMC + c0 + o4) = *(const uint2*)o;
  }
}

// ---------------------------------------------------------------------------
// phik: phi_k[b][e][n] = relu(sum_c Wt[e][c]*tk[b][n][c]); fused rowsum[b][e]
// A=Wt (gl_lds), B=tk (gl_lds). 128x128 tile, BK=32, K=256.
// ---------------------------------------------------------------------------
__global__ __launch_bounds__(256) void phik_kernel(
    const unsigned short* __restrict__ Wt, const unsigned short* __restrict__ tk,
    unsigned short* __restrict__ phi_k, float* __restrict__ rowsum) {
  __shared__ unsigned short As[128 * 32];  // [e][c]
  __shared__ unsigned short Bs[128 * 32];  // [n][c]
  const int b = blockIdx.z;
  const int n0 = blockIdx.x * 128;
  const int e0 = blockIdx.y * 128;
  const int t = threadIdx.x;
  const int lane = t & 63, wave = t >> 6;
  const int wr = wave >> 1, wc = wave & 1;
  const int q = lane >> 4, l15 = lane & 15;
  const unsigned short* Bb = tk + (size_t)b * NDIM * DIMC;
  const int a1row = t >> 2, a1k = (t & 3) << 3;
  f32x4 acc[4][4];
#pragma unroll
  for (int i = 0; i < 4; ++i)
#pragma unroll
    for (int j = 0; j < 4; ++j) acc[i][j] = (f32x4){0.f, 0.f, 0.f, 0.f};

  for (int k0 = 0; k0 < DIMC; k0 += 32) {
    __syncthreads();
    gl_lds16(Wt + (size_t)(e0 + a1row) * DIMC + k0 + a1k, &As[wave * 512]);
    gl_lds16(Wt + (size_t)(e0 + a1row + 64) * DIMC + k0 + a1k,
             &As[2048 + wave * 512]);
    gl_lds16(Bb + (size_t)(n0 + a1row) * DIMC + k0 + a1k, &Bs[wave * 512]);
    gl_lds16(Bb + (size_t)(n0 + a1row + 64) * DIMC + k0 + a1k,
             &Bs[2048 + wave * 512]);
    __syncthreads();
    bf16x8 a[4], bv[4];
#pragma unroll
    for (int i = 0; i < 4; ++i)
      a[i] = *(const bf16x8*)&As[(wr * 64 + i * 16 + l15) * 32 + q * 8];
#pragma unroll
    for (int j = 0; j < 4; ++j)
      bv[j] = *(const bf16x8*)&Bs[(wc * 64 + j * 16 + l15) * 32 + q * 8];
#pragma unroll
    for (int i = 0; i < 4; ++i)
#pragma unroll
      for (int j = 0; j < 4; ++j)
        acc[i][j] =
            __builtin_amdgcn_mfma_f32_16x16x32_bf16(a[i], bv[j], acc[i][j], 0, 0, 0);
  }
  // Epilogue: relu store [e][n] + rowsum partial (sum over this block's n's)
  unsigned short* dst = phi_k + (size_t)b * DIMC * NDIM;
#pragma unroll
  for (int i = 0; i < 4; ++i) {
#pragma unroll
    for (int r = 0; r < 4; ++r) {
      const int e = e0 + wr * 64 + i * 16 + q * 4 + r;
      float sp = 0.f;
#pragma unroll
      for (int j = 0; j < 4; ++j) {
        const int n = n0 + wc * 64 + j * 16 + l15;
        float v = acc[i][j][r];
        v = v > 0.f ? v : 0.f;
        sp += v;
        dst[(size_t)e * NDIM + n] = f2bf(v);
      }
      sp += __shfl_xor(sp, 1, 64);
      sp += __shfl_xor(sp, 2, 64);
      sp += __shfl_xor(sp, 4, 64);
      sp += __shfl_xor(sp, 8, 64);
      if (l15 == 0) atomicAdd(&rowsum[b * DIMC + e], sp);
    }
  }
}

// ---------------------------------------------------------------------------
// phiq: phi_q[b][m][e] = relu(sum_c tq[b][m][c]*Wt[e][c]); fused partial
// scale dot: scale_acc[b][m] += sum_e phi_q*rowsum[e]  (rowsum final here).
// ---------------------------------------------------------------------------
__global__ __launch_bounds__(256) void phiq_kernel(
    const unsigned short* __restrict__ tq, const unsigned short* __restrict__ Wt,
    const float* __restrict__ rowsum, unsigned short* __restrict__ phi_q,
    float* __restrict__ scale_acc) {
  __shared__ unsigned short As[128 * 32];  // [m][c]
  __shared__ unsigned short Bs[128 * 32];  // [e][c]
  __shared__ float rsL[128];
  const int b = blockIdx.z;
  const int m0 = blockIdx.x * 128;
  const int e0 = blockIdx.y * 128;
  const int t = threadIdx.x;
  const int lane = t & 63, wave = t >> 6;
  const int wr = wave >> 1, wc = wave & 1;
  const int q = lane >> 4, l15 = lane & 15;
  const unsigned short* Ab = tq + (size_t)b * MDIM * DIMC;
  const int a1row = t >> 2, a1k = (t & 3) << 3;
  if (t < 128) rsL[t] = rowsum[b * DIMC + e0 + t];
  f32x4 acc[4][4];
#pragma unroll
  for (int i = 0; i < 4; ++i)
#pragma unroll
    for (int j = 0; j < 4; ++j) acc[i][j] = (f32x4){0.f, 0.f, 0.f, 0.f};

  for (int k0 = 0; k0 < DIMC; k0 += 32) {
    __syncthreads();
    gl_lds16(Ab + (size_t)(m0 + a1row) * DIMC + k0 + a1k, &As[wave * 512]);
    gl_lds16(Ab + (size_t)(m0 + a1row + 64) * DIMC + k0 + a1k,
             &As[2048 + wave * 512]);
    gl_lds16(Wt + (size_t)(e0 + a1row) * DIMC + k0 + a1k, &Bs[wave * 512]);
    gl_lds16(Wt + (size_t)(e0 + a1row + 64) * DIMC + k0 + a1k,
             &Bs[2048 + wave * 512]);
    __syncthreads();
    bf16x8 a[4], bv[4];
#pragma unroll
    for (int i = 0; i < 4; ++i)
      a[i] = *(const bf16x8*)&As[(wr * 64 + i * 16 + l15) * 32 + q * 8];
#pragma unroll
    for (int j = 0; j < 4; ++j)
      bv[j] = *(const bf16x8*)&Bs[(wc * 64 + j * 16 + l15) * 32 + q * 8];
#pragma unroll
    for (int i = 0; i < 4; ++i)
#pragma unroll
      for (int j = 0; j < 4; ++j)
        acc[i][j] =
            __builtin_amdgcn_mfma_f32_16x16x32_bf16(a[i], bv[j], acc[i][j], 0, 0, 0);
  }
  // Epilogue: relu store [m][e] + partial dot with rowsum -> scale_acc[m]
  unsigned short* dst = phi_q + (size_t)b * MDIM * DIMC;
#pragma unroll
  for (int i = 0; i < 4; ++i) {
#pragma unroll
    for (int r = 0; r < 4; ++r) {
      const int m = m0 + wr * 64 + i * 16 + q * 4 + r;
      float sp = 0.f;
#pragma unroll
      for (int j = 0; j < 4; ++j) {
        const int e = e0 + wc * 64 + j * 16 + l15;
        float v = acc[i][j][r];
        v = v > 0.f ? v : 0.f;
        sp += v * rsL[wc * 64 + j * 16 + l15];
        dst[(size_t)m * DIMC + e] = f2bf(v);
      }
      sp += __shfl_xor(sp, 1, 64);
      sp += __shfl_xor(sp, 2, 64);
      sp += __shfl_xor(sp, 4, 64);
      sp += __shfl_xor(sp, 8, 64);
      if (l15 == 0) atomicAdd(&scale_acc[(size_t)b * MDIM + m], sp);
    }
  }
}

// ---------------------------------------------------------------------------
// kv partial: kv_acc[b][d][e] += sum_{n slice} value[b][d][n]*phi_k[b][e][n]
// grid (2,2,256): z = b*8+slice, K-slice 256. A: fp32 value converted in
// staging; B: bf16 gl_lds.
// ---------------------------------------------------------------------------
__global__ __launch_bounds__(256) void kv_kernel(
    const float* __restrict__ value, const unsigned short* __restrict__ phi_k,
    float* __restrict__ kv_acc) {
  __shared__ unsigned short As[128 * 40];  // [d][n] padded
  __shared__ unsigned short Bs[128 * 32];  // [e][n] gl_lds
  const int z = blockIdx.z;
  const int b = z >> 3, slice = z & 7;
  const int d0 = blockIdx.x * 128, e0 = blockIdx.y * 128;
  const int t = threadIdx.x;
  const int lane = t & 63, wave = t >> 6;
  const int wr = wave >> 1, wc = wave & 1;
  const int q = lane >> 4, l15 = lane & 15;
  const float* Ab = value + (size_t)b * DIMC * NDIM;
  const unsigned short* Bb = phi_k + (size_t)b * DIMC * NDIM;
  const int a1row = t >> 2, a1k = (t & 3) << 3;
  const int dl = t >> 1, nh = (t & 1) << 4;  // A staging: 128 rows x 32 n
  f32x4 acc[4][4];
#pragma unroll
  for (int i = 0; i < 4; ++i)
#pragma unroll
    for (int j = 0; j < 4; ++j) acc[i][j] = (f32x4){0.f, 0.f, 0.f, 0.f};

  const int nbeg = slice * 256;
  for (int n0 = nbeg; n0 < nbeg + 256; n0 += 32) {
    __syncthreads();
    {
      const float* src = Ab + (size_t)(d0 + dl) * NDIM + n0 + nh;
      float4 f0 = *(const float4*)(src + 0);
      float4 f1 = *(const float4*)(src + 4);
      float4 f2 = *(const float4*)(src + 8);
      float4 f3 = *(const float4*)(src + 12);
      unsigned short tmp[16] __attribute__((aligned(16)));
      tmp[0] = f2bf(f0.x); tmp[1] = f2bf(f0.y); tmp[2] = f2bf(f0.z); tmp[3] = f2bf(f0.w);
      tmp[4] = f2bf(f1.x); tmp[5] = f2bf(f1.y); tmp[6] = f2bf(f1.z); tmp[7] = f2bf(f1.w);
      tmp[8] = f2bf(f2.x); tmp[9] = f2bf(f2.y); tmp[10] = f2bf(f2.z); tmp[11] = f2bf(f2.w);
      tmp[12] = f2bf(f3.x); tmp[13] = f2bf(f3.y); tmp[14] = f2bf(f3.z); tmp[15] = f2bf(f3.w);
      *(uint4*)&As[dl * 40 + nh] = *(const uint4*)&tmp[0];
      *(uint4*)&As[dl * 40 + nh + 8] = *(const uint4*)&tmp[8];
    }
    gl_lds16(Bb + (size_t)(e0 + a1row) * NDIM + n0 + a1k, &Bs[wave * 512]);
    gl_lds16(Bb + (size_t)(e0 + a1row + 64) * NDIM + n0 + a1k,
             &Bs[2048 + wave * 512]);
    __syncthreads();
    bf16x8 a[4], bv[4];
#pragma unroll
    for (int i = 0; i < 4; ++i)
      a[i] = *(const bf16x8*)&As[(wr * 64 + i * 16 + l15) * 40 + q * 8];
#pragma unroll
    for (int j = 0; j < 4; ++j)
      bv[j] = *(const bf16x8*)&Bs[(wc * 64 + j * 16 + l15) * 32 + q * 8];
#pragma unroll
    for (int i = 0; i < 4; ++i)
#pragma unroll
      for (int j = 0; j < 4; ++j)
        acc[i][j] =
            __builtin_amdgcn_mfma_f32_16x16x32_bf16(a[i], bv[j], acc[i][j], 0, 0, 0);
  }
  float* kva = kv_acc + (size_t)b * DIMC * DIMC;
#pragma unroll
  for (int i = 0; i < 4; ++i)
#pragma unroll
    for (int j = 0; j < 4; ++j) {
      const int e = e0 + wc * 64 + j * 16 + l15;
#pragma unroll
      for (int r = 0; r < 4; ++r) {
        const int d = d0 + wr * 64 + i * 16 + q * 4 + r;
        atomicAdd(&kva[(size_t)d * DIMC + e], acc[i][j][r]);
      }
    }
}

// ---------------------------------------------------------------------------
// kv_t bf16 <- kv_acc fp32
// ---------------------------------------------------------------------------
__global__ __launch_bounds__(256) void kvcvt_kernel(
    const float* __restrict__ acc, unsigned short* __restrict__ kvt) {
  const size_t i = ((size_t)blockIdx.x * 256 + threadIdx.x) * 4;
  float4 a = *(const float4*)(acc + i);
  unsigned short t[4] __attribute__((aligned(8)));
  t[0] = f2bf(a.x); t[1] = f2bf(a.y); t[2] = f2bf(a.z); t[3] = f2bf(a.w);
  *(uint2*)(kvt + i) = *(const uint2*)t;
}

// ---------------------------------------------------------------------------
// out[b][d][m] = (1/(scale_acc[m]+1e-8)) * sum_e kv_t[d][e]*phi_q[m][e]
// ---------------------------------------------------------------------------
__global__ __launch_bounds__(256) void out_kernel(
    const unsigned short* __restrict__ kv_t,
    const unsigned short* __restrict__ phi_q,
    const float* __restrict__ scale_acc, float* __restrict__ out) {
  __shared__ unsigned short As[128 * 32];  // [d][e]
  __shared__ unsigned short Bs[128 * 32];  // [m][e]
  const int b = blockIdx.z;
  const int m0 = blockIdx.x * 128;
  const int d0 = blockIdx.y * 128;
  const int t = threadIdx.x;
  const int lane = t & 63, wave = t >> 6;
  const int wr = wave >> 1, wc = wave & 1;
  const int q = lane >> 4, l15 = lane & 15;
  const unsigned short* Ab = kv_t + (size_t)b * DIMC * DIMC;
  const unsigned short* Bb = phi_q + (size_t)b * MDIM * DIMC;
  const int a1row = t >> 2, a1k = (t & 3) << 3;
  f32x4 acc[4][4];
#pragma unroll
  for (int i = 0; i < 4; ++i)
#pragma unroll
    for (int j = 0; j < 4; ++j) acc[i][j] = (f32x4){0.f, 0.f, 0.f, 0.f};

  for (int k0 = 0; k0 < DIMC; k0 += 32) {
    __syncthreads();
    gl_lds16(Ab + (size_t)(d0 + a1row) * DIMC + k0 + a1k, &As[wave * 512]);
    gl_lds16(Ab + (size_t)(d0 + a1row + 64) * DIMC + k0 + a1k,
             &As[2048 + wave * 512]);
    gl_lds16(Bb + (size_t)(m0 + a1row) * DIMC + k0 + a1k, &Bs[wave * 512]);
    gl_lds16(Bb + (size_t)(m0 + a1row + 64) * DIMC + k0 + a1k,
             &Bs[2048 + wave * 512]);
    __syncthreads();
    bf16x8 a[4], bv[4];
#pragma unroll
    for (int i = 0; i < 4; ++i)
      a[i] = *(const bf16x8*)&As[(wr * 64 + i * 16 + l15) * 32 + q * 8];
#pragma unroll
    for (int j = 0; j < 4; ++j)
      bv[j] = *(const bf16x8*)&Bs[(wc * 64 + j * 16 + l15) * 32 + q * 8];
#pragma unroll
    for (int i = 0; i < 4; ++i)
#pragma unroll
      for (int j = 0; j < 4; ++j)
        acc[i][j] =
            __builtin_amdgcn_mfma_f32_16x16x32_bf16(a[i], bv[j], acc[i][j], 0, 0, 0);
  }
  float* ob = out + (size_t)b * DIMC * MDIM;
  const float* scb = scale_acc + (size_t)b * MDIM;
#pragma unroll
  for (int j = 0; j < 4; ++j) {
    const int m = m0 + wc * 64 + j * 16 + l15;
    const float sc = 1.f / (scb[m] + 1e-8f);
#pragma unroll
    for (int i = 0; i < 4; ++i) {
#pragma unroll
      for (int r = 0; r < 4; ++r) {
        const int d = d0 + wr * 64 + i * 16 + q * 4 + r;
        ob[(size_t)d * MDIM + m] = acc[i][j][r] * sc;
      }
    }
  }
}

extern "C" void kernel_launch(void* const* d_in, const int* in_sizes, int n_in,
                              void* d_out, int out_size, void* d_ws, size_t ws_size,
                              hipStream_t stream) {
  const float* query = (const float*)d_in[0];
  const float* key   = (const float*)d_in[1];
  const float* value = (const float*)d_in[2];
  const float* W     = (const float*)d_in[3];
  float* out = (float*)d_out;

  // Workspace (~132 MB). kv_acc aliases tq (tq dead after phiq).
  unsigned short* Wt    = (unsigned short*)d_ws;              // 64K elems
  unsigned short* tq    = Wt + 65536;                         // 16.8M elems
  unsigned short* tk    = tq + (size_t)BSZ * MDIM * DIMC;     // 16.8M
  unsigned short* phi_q = tk + (size_t)BSZ * NDIM * DIMC;     // 16.8M
  unsigned short* phi_k = phi_q + (size_t)BSZ * MDIM * DIMC;  // 16.8M
  unsigned short* kv_t  = phi_k + (size_t)BSZ * DIMC * NDIM;  // 2M
  float* rowsum    = (float*)(kv_t + (size_t)BSZ * DIMC * DIMC);  // 8K
  float* scale_acc = rowsum + BSZ * DIMC;                         // 64K
  float* kv_acc    = (float*)tq;                                  // 2M fp32

  // zero rowsum + scale_acc (contiguous)
  hipMemsetAsync(rowsum, 0, (size_t)(BSZ * DIMC + BSZ * MDIM) * sizeof(float),
                 stream);
  hipLaunchKernelGGL(wt_kernel, dim3(256), dim3(256), 0, stream, W, Wt);
  hipLaunchKernelGGL(trans_kernel, dim3(MDIM / 64, DIMC / 64, 64), dim3(256),
                     0, stream, query, key, tq, tk);
  hipLaunchKernelGGL(phik_kernel, dim3(NDIM / 128, DIMC / 128, BSZ), dim3(256),
                     0, stream, Wt, tk, phi_k, rowsum);
  hipLaunchKernelGGL(phiq_kernel, dim3(MDIM / 128, DIMC / 128, BSZ), dim3(256),
                     0, stream, tq, Wt, rowsum, phi_q, scale_acc);
  // tq is dead now; reuse as kv_acc
  hipMemsetAsync(kv_acc, 0, (size_t)BSZ * DIMC * DIMC * sizeof(float), stream);
  hipLaunchKernelGGL(kv_kernel, dim3(2, 2, BSZ * 8), dim3(256), 0, stream,
                     value, phi_k, kv_acc);
  hipLaunchKernelGGL(kvcvt_kernel, dim3(2048), dim3(256), 0, stream, kv_acc,
                     kv_t);
  hipLaunchKernelGGL(out_kernel, dim3(MDIM / 128, DIMC / 128, BSZ), dim3(256),
                     0, stream, kv_t, phi_q, scale_acc, out);
}